// Round 1
// baseline (1737.694 us; speedup 1.0000x reference)
//
#include <hip/hip_runtime.h>
#include <hip/hip_bf16.h>

// Grouped GEMM (FMoE expert linear), MI355X/gfx950.
// out[t,n] = sum_k inp[t,k] * weight[e(t),n,k] + bias[e(t),n]
// T=8192, K=2048, N=8192, E=16, equal 512-token groups.
// Strategy: m97-style 128x128x32 bf16-MFMA tile GEMM with fused fp32->bf16
// conversion during LDS staging (threshold 0.104 >> bf16 K=2048 error).

#define TOK   8192
#define KDIM  2048
#define NDIM  8192
#define NEXP  16

#define BM 128
#define BN 128
#define BK 32
#define LDSS 40   // shorts per LDS row: 32 + 8 pad (80 B, 16B-aligned, 2-way max bank alias)

typedef __attribute__((ext_vector_type(8))) short short8;
typedef __attribute__((ext_vector_type(4))) float f32x4;

// fp32 -> bf16 (round-half-up) pair pack: 1 add per elem + 1 v_perm per pair.
__device__ __forceinline__ unsigned pk2(float lo, float hi) {
    unsigned ul = __float_as_uint(lo) + 0x8000u;
    unsigned uh = __float_as_uint(hi) + 0x8000u;
    // dest bytes [0,1] = ul bytes [2,3]; dest bytes [2,3] = uh bytes [2,3]
    return __builtin_amdgcn_perm(uh, ul, 0x07060302u);
}
__device__ __forceinline__ uint2 pk4(float4 v) {
    uint2 r;
    r.x = pk2(v.x, v.y);
    r.y = pk2(v.z, v.w);
    return r;
}

__global__ __launch_bounds__(256) void moe_gemm(
    const float* __restrict__ inp,
    const float* __restrict__ weight,
    const float* __restrict__ bias,
    const int*   __restrict__ cnt,
    float*       __restrict__ out)
{
    __shared__ short sA[BM * LDSS];
    __shared__ short sB[BN * LDSS];

    const int tid = threadIdx.x;
    const int b   = blockIdx.x;

    // XCD-aware swizzle: xcd x owns n-tiles [x*8, x*8+8) of every expert.
    // Within an XCD, time order is (expert, n_local, m) with m innermost so
    // the 4 m-blocks sharing a weight slab are co-resident -> L2 weight reuse.
    const int x  = b & 7;
    const int j  = b >> 3;          // 0..511
    const int e  = j >> 5;          // expert 0..15
    const int t  = j & 31;
    const int nl = t >> 2;          // 0..7
    const int mi = t & 3;           // 0..3
    const int ntile = x * 8 + nl;   // 0..63

    // expert token start from device counts (harness: 512 each, BM-aligned)
    int m_start = 0;
    for (int i = 0; i < e; ++i) m_start += cnt[i];
    const int m0 = m_start + mi * BM;
    const int n0 = ntile * BN;

    const float* wexp = weight + (size_t)e * NDIM * KDIM;

    // staging mapping: 256 threads = 32 rows x 8 float4-cols per instruction
    const int tRow = tid >> 3;   // 0..31
    const int tCol = tid & 7;    // 0..7
    const float* aBase = inp  + (size_t)m0 * KDIM + tCol * 4;
    const float* bBase = wexp + (size_t)n0 * KDIM + tCol * 4;

    // wave mapping: 4 waves in 2x2, each computes 64x64 (4x4 of 16x16)
    const int wave = tid >> 6;
    const int lane = tid & 63;
    const int wm   = wave & 1;
    const int wn   = wave >> 1;
    const int r16  = lane & 15;
    const int quad = lane >> 4;

    f32x4 acc[4][4] = {};

    // prologue: load K-tile 0 into registers
    float4 ra[4], rb[4];
    #pragma unroll
    for (int i = 0; i < 4; ++i) {
        const int row = i * 32 + tRow;
        ra[i] = *(const float4*)(aBase + (size_t)row * KDIM);
        rb[i] = *(const float4*)(bBase + (size_t)row * KDIM);
    }

    const int KSTEPS = KDIM / BK;   // 64
    for (int kt = 0; kt < KSTEPS; ++kt) {
        __syncthreads();   // previous iteration's fragment reads done
        #pragma unroll
        for (int i = 0; i < 4; ++i) {
            const int row = i * 32 + tRow;
            *(uint2*)&sA[row * LDSS + tCol * 4] = pk4(ra[i]);
            *(uint2*)&sB[row * LDSS + tCol * 4] = pk4(rb[i]);
        }
        __syncthreads();   // tiles visible

        // prefetch next K-tile into registers (overlaps with MFMA below)
        if (kt + 1 < KSTEPS) {
            const int koff = (kt + 1) * BK;
            #pragma unroll
            for (int i = 0; i < 4; ++i) {
                const int row = i * 32 + tRow;
                ra[i] = *(const float4*)(aBase + (size_t)row * KDIM + koff);
                rb[i] = *(const float4*)(bBase + (size_t)row * KDIM + koff);
            }
        }

        // fragments: A[m=lane&15][k=quad*8+j], B^T row n=lane&15 same layout
        short8 af[4], bf[4];
        #pragma unroll
        for (int mt = 0; mt < 4; ++mt)
            af[mt] = *(const short8*)&sA[(wm * 64 + mt * 16 + r16) * LDSS + quad * 8];
        #pragma unroll
        for (int nt = 0; nt < 4; ++nt)
            bf[nt] = *(const short8*)&sB[(wn * 64 + nt * 16 + r16) * LDSS + quad * 8];

        #pragma unroll
        for (int mt = 0; mt < 4; ++mt)
            #pragma unroll
            for (int nt = 0; nt < 4; ++nt)
                acc[mt][nt] = __builtin_amdgcn_mfma_f32_16x16x32_bf16(
                    af[mt], bf[nt], acc[mt][nt], 0, 0, 0);
    }

    // epilogue: C/D layout col=lane&15 (n), row=quad*4+reg (m); add bias
    #pragma unroll
    for (int nt = 0; nt < 4; ++nt) {
        const int n = n0 + wn * 64 + nt * 16 + r16;
        const float bv = bias[(size_t)e * NDIM + n];
        #pragma unroll
        for (int mt = 0; mt < 4; ++mt) {
            #pragma unroll
            for (int r = 0; r < 4; ++r) {
                const int m = m0 + wm * 64 + mt * 16 + quad * 4 + r;
                out[(size_t)m * NDIM + n] = acc[mt][nt][r] + bv;
            }
        }
    }
}

extern "C" void kernel_launch(void* const* d_in, const int* in_sizes, int n_in,
                              void* d_out, int out_size, void* d_ws, size_t ws_size,
                              hipStream_t stream) {
    const float* inp    = (const float*)d_in[0];
    const float* weight = (const float*)d_in[1];
    const float* bias   = (const float*)d_in[2];
    const int*   cnt    = (const int*)d_in[3];
    float* out = (float*)d_out;

    const int grid = (TOK / BM) * (NDIM / BN);   // 64 * 64 = 4096
    hipLaunchKernelGGL(moe_gemm, dim3(grid), dim3(256), 0, stream,
                       inp, weight, bias, cnt, out);
}